// Round 7
// baseline (361.299 us; speedup 1.0000x reference)
//
#include <hip/hip_runtime.h>
#include <hip/hip_bf16.h>
#include <math.h>

#define NB 8          // batch
#define NN 1024       // nodes
#define NI 64         // input feat
#define EHC 4         // E*H
#define ND 128        // hidden
#define NO 64         // outputs
#define FIN1 512      // E*H*D
#define BN 8192       // B*N

typedef __attribute__((ext_vector_type(8))) short short8;
typedef __attribute__((ext_vector_type(4))) float f32x4;
typedef __attribute__((ext_vector_type(4))) unsigned int u32x4;

__device__ __forceinline__ unsigned short f2bf(float f) {
    union { float f; unsigned u; } v; v.f = f;
    unsigned r = v.u + 0x7FFF + ((v.u >> 16) & 1);
    return (unsigned short)(r >> 16);
}
// pack two floats to bf16 pair (round-half-up) in one v_perm
__device__ __forceinline__ unsigned pack2bf(float f0, float f1) {
    union { float f; unsigned u; } a, b;
    a.f = f0; b.f = f1;
    return __builtin_amdgcn_perm(b.u + 0x8000u, a.u + 0x8000u, 0x07060302u);
}

// ---------------- prep: W0,W1 -> bf16 WT[eh][d][k]; Wemb -> WembT[d][k] ----------------
__global__ void prepTk(const float* __restrict__ W0, const float* __restrict__ W1,
                       const float* __restrict__ Wemb, unsigned short* __restrict__ W0T,
                       unsigned short* __restrict__ W1T, unsigned short* __restrict__ WembT) {
    int idx = blockIdx.x * 256 + threadIdx.x;
    if (idx < EHC * ND * ND) {
        int eh = idx >> 14, d = (idx >> 7) & 127, k = idx & 127;
        W0T[idx] = f2bf(W0[((size_t)(eh * ND + k)) * ND + d]);
    }
    int idx1 = idx - EHC * ND * ND;
    if (idx1 >= 0 && idx1 < EHC * ND * FIN1) {
        int eh = idx1 >> 16;
        int r = idx1 & 65535;
        int d = r >> 9, k = r & 511;
        W1T[idx1] = f2bf(W1[((size_t)(eh * FIN1 + k)) * ND + d]);
    }
    int idx2 = idx - (EHC * ND * ND + EHC * ND * FIN1);
    if (idx2 >= 0 && idx2 < ND * NI) {
        int d = idx2 >> 6, k = idx2 & 63;
        WembT[idx2] = f2bf(Wemb[k * ND + d]);
    }
}

// ---------------- fused embed + layer-0 filter GEMM + s1/s2 epilogue ----------------
// stores Wh in fp32 [ehb][d][i]
__global__ __launch_bounds__(256, 4) void embwh0k(
    const float* __restrict__ nodes, const unsigned short* __restrict__ WembT,
    const float* __restrict__ bemb, const unsigned short* __restrict__ W0T,
    float* __restrict__ Whf, const float* __restrict__ a1w,
    const float* __restrict__ a1b, const float* __restrict__ a2w,
    const float* __restrict__ a2b, float* __restrict__ s1, float* __restrict__ s2) {
    int id = blockIdx.x;
    int g = id & 7, s_ = id >> 3;
    int eh = s_ & 3;
    int row0 = ((s_ >> 2) * 8 + g) * 32;
    int t = threadIdx.x;
    int w = t >> 6, lane = t & 63;
    int m = lane & 15, quad = lane >> 4;

    __shared__ unsigned short stateL[32 * 136];

    // ---- embed via MFMA: state = relu(nodes @ Wemb + bemb) ----
    f32x4 accE[2][2];
#pragma unroll
    for (int mt = 0; mt < 2; ++mt)
#pragma unroll
        for (int nt = 0; nt < 2; ++nt) accE[mt][nt] = (f32x4){0.f, 0.f, 0.f, 0.f};
#pragma unroll
    for (int kt = 0; kt < 2; ++kt) {
        short8 aE[2], bE[2];
#pragma unroll
        for (int mt = 0; mt < 2; ++mt) {
            const float* np = nodes + (size_t)(row0 + mt * 16 + m) * NI + kt * 32 + quad * 8;
            f32x4 v0 = *(const f32x4*)np;
            f32x4 v1 = *(const f32x4*)(np + 4);
            union { unsigned us[4]; short8 s8; } pk;
#pragma unroll
            for (int r = 0; r < 2; ++r) {
                pk.us[r] = pack2bf(v0[2 * r], v0[2 * r + 1]);
                pk.us[r + 2] = pack2bf(v1[2 * r], v1[2 * r + 1]);
            }
            aE[mt] = pk.s8;
        }
#pragma unroll
        for (int nt = 0; nt < 2; ++nt)
            bE[nt] = *(const short8*)(WembT + (w * 32 + nt * 16 + m) * NI + kt * 32 + quad * 8);
#pragma unroll
        for (int mt = 0; mt < 2; ++mt)
#pragma unroll
            for (int nt = 0; nt < 2; ++nt)
                accE[mt][nt] =
                    __builtin_amdgcn_mfma_f32_16x16x32_bf16(aE[mt], bE[nt], accE[mt][nt], 0, 0, 0);
    }
#pragma unroll
    for (int mt = 0; mt < 2; ++mt)
#pragma unroll
        for (int nt = 0; nt < 2; ++nt) {
            int d = w * 32 + nt * 16 + m;
            float bb = bemb[d];
#pragma unroll
            for (int r = 0; r < 4; ++r) {
                float v = fmaxf(accE[mt][nt][r] + bb, 0.f);
                stateL[(mt * 16 + quad * 4 + r) * 136 + d] = f2bf(v);
            }
        }
    __syncthreads();

    // ---- main GEMM: Wh = state @ W0[eh], K=128, A from LDS ----
    f32x4 acc[2][2];
#pragma unroll
    for (int mt = 0; mt < 2; ++mt)
#pragma unroll
        for (int nt = 0; nt < 2; ++nt) acc[mt][nt] = (f32x4){0.f, 0.f, 0.f, 0.f};
#pragma unroll
    for (int k0 = 0; k0 < ND; k0 += 32) {
        short8 a[2], b[2];
#pragma unroll
        for (int mt = 0; mt < 2; ++mt)
            a[mt] = *(const short8*)&stateL[(mt * 16 + m) * 136 + k0 + quad * 8];
#pragma unroll
        for (int nt = 0; nt < 2; ++nt)
            b[nt] = *(const short8*)(W0T + ((size_t)(eh * ND + w * 32 + nt * 16 + m)) * ND +
                                     k0 + quad * 8);
#pragma unroll
        for (int mt = 0; mt < 2; ++mt)
#pragma unroll
            for (int nt = 0; nt < 2; ++nt)
                acc[mt][nt] =
                    __builtin_amdgcn_mfma_f32_16x16x32_bf16(a[mt], b[nt], acc[mt][nt], 0, 0, 0);
    }

    // ---- epilogue: store Wh fp32 + fused s1/s2 ----
    int b_ = row0 >> 10, i0b = row0 & 1023;
    int ehb = eh * NB + b_;
#pragma unroll
    for (int mt = 0; mt < 2; ++mt)
#pragma unroll
        for (int nt = 0; nt < 2; ++nt) {
            int d = w * 32 + nt * 16 + m;
            int i = i0b + mt * 16 + quad * 4;
            *(f32x4*)(Whf + (((size_t)ehb) * ND + d) * NN + i) = acc[mt][nt];
        }
    float w1a = a1w[eh * ND + w * 32 + m], w1b = a1w[eh * ND + w * 32 + 16 + m];
    float w2a = a2w[eh * ND + w * 32 + m], w2b = a2w[eh * ND + w * 32 + 16 + m];
    float p1[2][4], p2[2][4];
#pragma unroll
    for (int mt = 0; mt < 2; ++mt)
#pragma unroll
        for (int r = 0; r < 4; ++r) {
            p1[mt][r] = acc[mt][0][r] * w1a + acc[mt][1][r] * w1b;
            p2[mt][r] = acc[mt][0][r] * w2a + acc[mt][1][r] * w2b;
        }
#pragma unroll
    for (int off = 8; off >= 1; off >>= 1)
#pragma unroll
        for (int mt = 0; mt < 2; ++mt)
#pragma unroll
            for (int r = 0; r < 4; ++r) {
                p1[mt][r] += __shfl_xor(p1[mt][r], off);
                p2[mt][r] += __shfl_xor(p2[mt][r], off);
            }
    __shared__ float sred[2][4][4][8];
    if (m == 0) {
#pragma unroll
        for (int mt = 0; mt < 2; ++mt)
#pragma unroll
            for (int r = 0; r < 4; ++r) {
                sred[0][w][quad][mt * 4 + r] = p1[mt][r];
                sred[1][w][quad][mt * 4 + r] = p2[mt][r];
            }
    }
    __syncthreads();
    if (t < 32) {
        int mt = t >> 4, quad2 = (t >> 2) & 3, r = t & 3;
        int c = mt * 4 + r;
        float v = sred[0][0][quad2][c] + sred[0][1][quad2][c] + sred[0][2][quad2][c] +
                  sred[0][3][quad2][c];
        s1[(size_t)ehb * NN + i0b + t] = v + a1b[eh];
    } else if (t < 64) {
        int tl = t - 32;
        int mt = tl >> 4, quad2 = (tl >> 2) & 3, r = tl & 3;
        int c = mt * 4 + r;
        float v = sred[1][0][quad2][c] + sred[1][1][quad2][c] + sred[1][2][quad2][c] +
                  sred[1][3][quad2][c];
        s2[(size_t)ehb * NN + i0b + tl] = v + a2b[eh];
    }
}

// ---------------- layer-1 filter GEMM (K=512), stores Wh fp32 + s1/s2 ----------------
__global__ __launch_bounds__(256, 4) void whgemm1k(
    const unsigned short* __restrict__ state, const unsigned short* __restrict__ WT,
    float* __restrict__ Whf, const float* __restrict__ a1w,
    const float* __restrict__ a1b, const float* __restrict__ a2w,
    const float* __restrict__ a2b, float* __restrict__ s1, float* __restrict__ s2) {
    int id = blockIdx.x;
    int g = id & 7, s_ = id >> 3;
    int eh = s_ & 3;
    int row0 = ((s_ >> 2) * 8 + g) * 32;
    int t = threadIdx.x;
    int w = t >> 6, lane = t & 63;
    int m = lane & 15, quad = lane >> 4;

    f32x4 acc[2][2];
#pragma unroll
    for (int mt = 0; mt < 2; ++mt)
#pragma unroll
        for (int nt = 0; nt < 2; ++nt) acc[mt][nt] = (f32x4){0.f, 0.f, 0.f, 0.f};

    const unsigned short* Ab = state + (size_t)(row0 + m) * FIN1 + quad * 8;
    const unsigned short* Bb = WT + ((size_t)eh * ND + w * 32 + m) * FIN1 + quad * 8;
#pragma unroll 4
    for (int k0 = 0; k0 < FIN1; k0 += 32) {
        short8 a[2], b[2];
#pragma unroll
        for (int mt = 0; mt < 2; ++mt)
            a[mt] = *(const short8*)(Ab + (size_t)mt * 16 * FIN1 + k0);
#pragma unroll
        for (int nt = 0; nt < 2; ++nt)
            b[nt] = *(const short8*)(Bb + (size_t)nt * 16 * FIN1 + k0);
#pragma unroll
        for (int mt = 0; mt < 2; ++mt)
#pragma unroll
            for (int nt = 0; nt < 2; ++nt)
                acc[mt][nt] =
                    __builtin_amdgcn_mfma_f32_16x16x32_bf16(a[mt], b[nt], acc[mt][nt], 0, 0, 0);
    }
    int b_ = row0 >> 10, i0b = row0 & 1023;
    int ehb = eh * NB + b_;
#pragma unroll
    for (int mt = 0; mt < 2; ++mt)
#pragma unroll
        for (int nt = 0; nt < 2; ++nt) {
            int d = w * 32 + nt * 16 + m;
            int i = i0b + mt * 16 + quad * 4;
            *(f32x4*)(Whf + (((size_t)ehb) * ND + d) * NN + i) = acc[mt][nt];
        }
    float w1a = a1w[eh * ND + w * 32 + m], w1b = a1w[eh * ND + w * 32 + 16 + m];
    float w2a = a2w[eh * ND + w * 32 + m], w2b = a2w[eh * ND + w * 32 + 16 + m];
    float p1[2][4], p2[2][4];
#pragma unroll
    for (int mt = 0; mt < 2; ++mt)
#pragma unroll
        for (int r = 0; r < 4; ++r) {
            p1[mt][r] = acc[mt][0][r] * w1a + acc[mt][1][r] * w1b;
            p2[mt][r] = acc[mt][0][r] * w2a + acc[mt][1][r] * w2b;
        }
#pragma unroll
    for (int off = 8; off >= 1; off >>= 1)
#pragma unroll
        for (int mt = 0; mt < 2; ++mt)
#pragma unroll
            for (int r = 0; r < 4; ++r) {
                p1[mt][r] += __shfl_xor(p1[mt][r], off);
                p2[mt][r] += __shfl_xor(p2[mt][r], off);
            }
    __shared__ float sred[2][4][4][8];
    if (m == 0) {
#pragma unroll
        for (int mt = 0; mt < 2; ++mt)
#pragma unroll
            for (int r = 0; r < 4; ++r) {
                sred[0][w][quad][mt * 4 + r] = p1[mt][r];
                sred[1][w][quad][mt * 4 + r] = p2[mt][r];
            }
    }
    __syncthreads();
    if (t < 32) {
        int mt = t >> 4, quad2 = (t >> 2) & 3, r = t & 3;
        int c = mt * 4 + r;
        float v = sred[0][0][quad2][c] + sred[0][1][quad2][c] + sred[0][2][quad2][c] +
                  sred[0][3][quad2][c];
        s1[(size_t)ehb * NN + i0b + t] = v + a1b[eh];
    } else if (t < 64) {
        int tl = t - 32;
        int mt = tl >> 4, quad2 = (tl >> 2) & 3, r = tl & 3;
        int c = mt * 4 + r;
        float v = sred[1][0][quad2][c] + sred[1][1][quad2][c] + sred[1][2][quad2][c] +
                  sred[1][3][quad2][c];
        s2[(size_t)ehb * NN + i0b + tl] = v + a2b[eh];
    }
}

// ---------------- column sums + cache P bf16: Spart[ic][ehb][j], P[ehb][i][j] ----------
__global__ __launch_bounds__(256, 4) void colsumk(const float* __restrict__ edges,
                                                  const float* __restrict__ s1,
                                                  const float* __restrict__ s2,
                                                  float* __restrict__ Spart,
                                                  unsigned* __restrict__ Pbuf) {
    int jt = blockIdx.x, b = blockIdx.y, ic = blockIdx.z;
    int t = threadIdx.x;
    int jp = t & 31, is = t >> 5;          // j-pair, i-chunk (16 i each)
    int j = jt * 64 + jp * 2;
    __shared__ float s1L[4][128];
    for (int idx = t; idx < 512; idx += 256) {
        int eh = idx >> 7;
        s1L[eh][idx & 127] = s1[((size_t)eh * NB + b) * NN + ic * 128 + (idx & 127)];
    }
    __syncthreads();
    float s2v[4][2], acc4[4][2];
#pragma unroll
    for (int eh = 0; eh < 4; ++eh) {
        s2v[eh][0] = s2[((size_t)eh * NB + b) * NN + j];
        s2v[eh][1] = s2[((size_t)eh * NB + b) * NN + j + 1];
        acc4[eh][0] = 0.f;
        acc4[eh][1] = 0.f;
    }
    const float4* ep = (const float4*)edges +
                       (size_t)(b * NN + ic * 128 + is * 16) * (NN / 2) + jt * 32 + jp;
#pragma unroll 2
    for (int ii = 0; ii < 16; ++ii) {
        float4 ev = ep[(size_t)ii * (NN / 2)];   // (e0,e1)@j ; (e0,e1)@j+1
        int i = ic * 128 + is * 16 + ii;
#pragma unroll
        for (int eh = 0; eh < 4; ++eh) {
            float sv = s1L[eh][is * 16 + ii];
            float x0 = sv + s2v[eh][0];
            x0 = fmaxf(x0, 0.2f * x0);
            float p0 = __expf(x0 + (eh < 2 ? ev.x : ev.y));
            float x1 = sv + s2v[eh][1];
            x1 = fmaxf(x1, 0.2f * x1);
            float p1v = __expf(x1 + (eh < 2 ? ev.z : ev.w));
            acc4[eh][0] += p0;
            acc4[eh][1] += p1v;
            Pbuf[((size_t)(eh * NB + b) * NN + i) * (NN / 2) + jt * 32 + jp] =
                pack2bf(p0, p1v);
        }
    }
    __shared__ float red[8][4][64];  // [is][eh][jl]
#pragma unroll
    for (int eh = 0; eh < 4; ++eh) {
        red[is][eh][jp * 2] = acc4[eh][0];
        red[is][eh][jp * 2 + 1] = acc4[eh][1];
    }
    __syncthreads();
    if (t < 256) {
        int eho = t >> 6, jlo = t & 63;
        float Sv = 0.f;
#pragma unroll
        for (int isx = 0; isx < 8; ++isx) Sv += red[isx][eho][jlo];
        Spart[(((size_t)ic * EHC + eho) * NB + b) * NN + jt * 64 + jlo] = Sv;
    }
}

// ---------------- whnk: Whn[ehb][d][j] = bf16(Whf[ehb][d][j] / S_j) ----------------
__global__ __launch_bounds__(256) void whnk(const float* __restrict__ Whf,
                                            const float* __restrict__ Spart,
                                            unsigned short* __restrict__ Whn) {
    int blk = blockIdx.x;          // 256 = 32 ehb * 8 jc
    int ehb = blk & 31, jc = blk >> 5;
    int t = threadIdx.x;
    __shared__ float rS[128];
    if (t < 128) {
        int j = jc * 128 + t;
        const size_t pstr = (size_t)EHC * NB * NN;
        float S = 0.f;
#pragma unroll
        for (int ic = 0; ic < 8; ++ic) S += Spart[(size_t)ic * pstr + (size_t)ehb * NN + j];
        rS[t] = 1.f / S;
    }
    __syncthreads();
#pragma unroll
    for (int it = 0; it < 8; ++it) {
        int idx = it * 256 + t;
        int d = idx >> 4, jq = idx & 15;
        int j = jc * 128 + jq * 8;
        const float* wp = Whf + ((size_t)ehb * ND + d) * NN + j;
        f32x4 v0 = *(const f32x4*)wp;
        f32x4 v1 = *(const f32x4*)(wp + 4);
        u32x4 o;
        o[0] = pack2bf(v0[0] * rS[jq * 8 + 0], v0[1] * rS[jq * 8 + 1]);
        o[1] = pack2bf(v0[2] * rS[jq * 8 + 2], v0[3] * rS[jq * 8 + 3]);
        o[2] = pack2bf(v1[0] * rS[jq * 8 + 4], v1[1] * rS[jq * 8 + 5]);
        o[3] = pack2bf(v1[2] * rS[jq * 8 + 6], v1[3] * rS[jq * 8 + 7]);
        *(u32x4*)(Whn + ((size_t)ehb * ND + d) * NN + j) = o;
    }
}

// ---------------- msg: pure bf16 GEMM  C[d][i] = sum_j Whn[d,j] * P[i,j] ----------------
// block: M=128 d (4 waves x 32), N=32 i, K=1024. Direct global->reg, no LDS.
__global__ __launch_bounds__(256, 4) void msgk(const unsigned short* __restrict__ Whn,
                                               const unsigned short* __restrict__ Pbuf,
                                               const float* __restrict__ sb,
                                               unsigned short* __restrict__ out0,
                                               float* __restrict__ out1, int mode) {
    int id = blockIdx.x;
    int ehb = id & 31;             // 32 blocks sharing Whn land on same XCD slots
    int it = id >> 5;              // 0..31
    int eh = ehb >> 3, b = ehb & 7;
    int i0 = it * 32;
    int t = threadIdx.x;
    int w = t >> 6, lane = t & 63;
    int m = lane & 15, quad = lane >> 4;

    f32x4 acc[2][2];               // [mt: d 16s][nt: i 16s]
#pragma unroll
    for (int mt = 0; mt < 2; ++mt)
#pragma unroll
        for (int nt = 0; nt < 2; ++nt) acc[mt][nt] = (f32x4){0.f, 0.f, 0.f, 0.f};

    const unsigned short* Ab = Whn + ((size_t)ehb * ND + w * 32 + m) * NN + quad * 8;
    const unsigned short* Bb = Pbuf ? (const unsigned short*)0 : (const unsigned short*)0;
    const unsigned short* Pb = Pbuf + ((size_t)ehb * NN + i0 + m) * NN + quad * 8;
    (void)Bb;
#pragma unroll 4
    for (int k0 = 0; k0 < NN; k0 += 32) {
        short8 a[2], bv[2];
#pragma unroll
        for (int mt = 0; mt < 2; ++mt)
            a[mt] = *(const short8*)(Ab + (size_t)mt * 16 * NN + k0);
#pragma unroll
        for (int nt = 0; nt < 2; ++nt)
            bv[nt] = *(const short8*)(Pb + (size_t)nt * 16 * NN + k0);
#pragma unroll
        for (int mt = 0; mt < 2; ++mt)
#pragma unroll
            for (int nt = 0; nt < 2; ++nt)
                acc[mt][nt] =
                    __builtin_amdgcn_mfma_f32_16x16x32_bf16(a[mt], bv[nt], acc[mt][nt], 0, 0, 0);
    }

    // epilogue: C row(quad*4+r)=d (A side), col(m)=i (B side)
#pragma unroll
    for (int mt = 0; mt < 2; ++mt) {
        int d0 = w * 32 + mt * 16 + quad * 4;
        f32x4 sbv = *(const f32x4*)&sb[eh * ND + d0];
#pragma unroll
        for (int nt = 0; nt < 2; ++nt) {
            int i = i0 + nt * 16 + m;
            if (mode == 0) {
                union { unsigned us[2]; unsigned long long u64; } pk;
                pk.us[0] = pack2bf(acc[mt][nt][0] + sbv[0], acc[mt][nt][1] + sbv[1]);
                pk.us[1] = pack2bf(acc[mt][nt][2] + sbv[2], acc[mt][nt][3] + sbv[3]);
                *(unsigned long long*)(out0 + (size_t)(b * NN + i) * FIN1 + eh * ND + d0) =
                    pk.u64;
            } else {
                f32x4 vv;
#pragma unroll
                for (int r = 0; r < 4; ++r) {
                    float v = acc[mt][nt][r] + sbv[r];
                    vv[r] = v > 0.f ? v : expm1f(v);
                }
                *(f32x4*)(out1 + ((size_t)ehb * NN + i) * ND + d0) = vv;
            }
        }
    }
}

// ---------------- final: out = mean_eh(m1) @ Wout + bout (fused) ----------------
__global__ __launch_bounds__(256) void finalk(const float* __restrict__ m1,
                                              const float* __restrict__ Wout,
                                              const float* __restrict__ bout,
                                              float* __restrict__ out) {
    int row0 = blockIdx.x * 16;
    int t = threadIdx.x;
    __shared__ float sF[16 * ND];
    __shared__ float wL[ND * NO];
    const size_t str = (size_t)BN * ND;
    for (int idx = t; idx < 16 * ND; idx += 256) {
        size_t r = (size_t)row0 * ND + idx;
        sF[idx] = 0.25f * (m1[r] + m1[r + str] + m1[r + 2 * str] + m1[r + 3 * str]);
    }
    for (int idx = t; idx < ND * NO; idx += 256) wL[idx] = Wout[idx];
    __syncthreads();
    int o = t & 63;
    int rr = t >> 6;
    float bo = bout[o];
#pragma unroll
    for (int q = 0; q < 4; ++q) {
        int r = rr * 4 + q;
        float acc = 0.f;
#pragma unroll 4
        for (int d = 0; d < ND; ++d) acc += sF[r * ND + d] * wL[d * NO + o];
        out[(size_t)(row0 + r) * NO + o] = acc + bo;
    }
}

extern "C" void kernel_launch(void* const* d_in, const int* in_sizes, int n_in,
                              void* d_out, int out_size, void* d_ws, size_t ws_size,
                              hipStream_t stream) {
    const float* nodes = (const float*)d_in[0];
    const float* edges = (const float*)d_in[1];
    const float* Wemb = (const float*)d_in[2];
    const float* bemb = (const float*)d_in[3];
    const float* W0 = (const float*)d_in[4];
    const float* A1w0 = (const float*)d_in[5];
    const float* A1b0 = (const float*)d_in[6];
    const float* A2w0 = (const float*)d_in[7];
    const float* A2b0 = (const float*)d_in[8];
    const float* SB0 = (const float*)d_in[9];
    const float* W1 = (const float*)d_in[10];
    const float* A1w1 = (const float*)d_in[11];
    const float* A1b1 = (const float*)d_in[12];
    const float* A2w1 = (const float*)d_in[13];
    const float* A2b1 = (const float*)d_in[14];
    const float* SB1 = (const float*)d_in[15];
    const float* Wout = (const float*)d_in[16];
    const float* bout = (const float*)d_in[17];
    float* out = (float*)d_out;

    char* p = (char*)d_ws;
    auto alloc = [&](size_t bytes) {
        char* r = p;
        p += (bytes + 255) & ~(size_t)255;
        return r;
    };
    unsigned short* W0T = (unsigned short*)alloc((size_t)EHC * ND * ND * 2);
    unsigned short* W1T = (unsigned short*)alloc((size_t)EHC * ND * FIN1 * 2);
    unsigned short* WembT = (unsigned short*)alloc((size_t)ND * NI * 2);
    float* Whf = (float*)alloc((size_t)EHC * BN * ND * 4);
    unsigned short* Whn = (unsigned short*)alloc((size_t)EHC * BN * ND * 2);
    unsigned* Pbuf = (unsigned*)alloc((size_t)EHC * NB * NN * (NN / 2) * 4);
    unsigned short* state1 = (unsigned short*)alloc((size_t)BN * FIN1 * 2);
    float* s1b = (float*)alloc((size_t)EHC * BN * 4);
    float* s2b = (float*)alloc((size_t)EHC * BN * 4);
    float* Spart = (float*)alloc((size_t)8 * EHC * BN * 4);
    float* m1 = (float*)alloc((size_t)EHC * BN * ND * 4);

    prepTk<<<1312, 256, 0, stream>>>(W0, W1, Wemb, W0T, W1T, WembT);
    // layer 0
    embwh0k<<<1024, 256, 0, stream>>>(nodes, WembT, bemb, W0T, Whf, A1w0, A1b0, A2w0, A2b0,
                                      s1b, s2b);
    colsumk<<<dim3(NN / 64, NB, 8), 256, 0, stream>>>(edges, s1b, s2b, Spart, Pbuf);
    whnk<<<256, 256, 0, stream>>>(Whf, Spart, Whn);
    msgk<<<1024, 256, 0, stream>>>(Whn, (const unsigned short*)Pbuf, SB0, state1, m1, 0);
    // layer 1
    whgemm1k<<<1024, 256, 0, stream>>>(state1, W1T, Whf, A1w1, A1b1, A2w1, A2b1, s1b, s2b);
    colsumk<<<dim3(NN / 64, NB, 8), 256, 0, stream>>>(edges, s1b, s2b, Spart, Pbuf);
    whnk<<<256, 256, 0, stream>>>(Whf, Spart, Whn);
    msgk<<<1024, 256, 0, stream>>>(Whn, (const unsigned short*)Pbuf, SB1, state1, m1, 1);
    // head
    finalk<<<BN / 16, 256, 0, stream>>>(m1, Wout, bout, out);
}

// Round 8
// 330.617 us; speedup vs baseline: 1.0928x; 1.0928x over previous
//
#include <hip/hip_runtime.h>
#include <hip/hip_bf16.h>
#include <math.h>

#define NB 8          // batch
#define NN 1024       // nodes
#define NI 64         // input feat
#define EHC 4         // E*H
#define ND 128        // hidden
#define NO 64         // outputs
#define FIN1 512      // E*H*D
#define BN 8192       // B*N

typedef __attribute__((ext_vector_type(8))) short short8;
typedef __attribute__((ext_vector_type(4))) float f32x4;
typedef __attribute__((ext_vector_type(4))) unsigned int u32x4;

__device__ __forceinline__ unsigned short f2bf(float f) {
    union { float f; unsigned u; } v; v.f = f;
    unsigned r = v.u + 0x7FFF + ((v.u >> 16) & 1);
    return (unsigned short)(r >> 16);
}
// pack two floats to bf16 pair (round-half-up) in one v_perm
__device__ __forceinline__ unsigned pack2bf(float f0, float f1) {
    union { float f; unsigned u; } a, b;
    a.f = f0; b.f = f1;
    return __builtin_amdgcn_perm(b.u + 0x8000u, a.u + 0x8000u, 0x07060302u);
}

// ---------------- prep: W0,W1 -> bf16 WT[eh][d][k]; Wemb -> WembT[d][k] ----------------
__global__ void prepTk(const float* __restrict__ W0, const float* __restrict__ W1,
                       const float* __restrict__ Wemb, unsigned short* __restrict__ W0T,
                       unsigned short* __restrict__ W1T, unsigned short* __restrict__ WembT) {
    int idx = blockIdx.x * 256 + threadIdx.x;
    if (idx < EHC * ND * ND) {
        int eh = idx >> 14, d = (idx >> 7) & 127, k = idx & 127;
        W0T[idx] = f2bf(W0[((size_t)(eh * ND + k)) * ND + d]);
    }
    int idx1 = idx - EHC * ND * ND;
    if (idx1 >= 0 && idx1 < EHC * ND * FIN1) {
        int eh = idx1 >> 16;
        int r = idx1 & 65535;
        int d = r >> 9, k = r & 511;
        W1T[idx1] = f2bf(W1[((size_t)(eh * FIN1 + k)) * ND + d]);
    }
    int idx2 = idx - (EHC * ND * ND + EHC * ND * FIN1);
    if (idx2 >= 0 && idx2 < ND * NI) {
        int d = idx2 >> 6, k = idx2 & 63;
        WembT[idx2] = f2bf(Wemb[k * ND + d]);
    }
}

// ---------------- fused embed + layer-0 filter GEMM + s1/s2 epilogue ----------------
// stores Wh in fp32 [ehb][d][i]
__global__ __launch_bounds__(256, 4) void embwh0k(
    const float* __restrict__ nodes, const unsigned short* __restrict__ WembT,
    const float* __restrict__ bemb, const unsigned short* __restrict__ W0T,
    float* __restrict__ Whf, const float* __restrict__ a1w,
    const float* __restrict__ a1b, const float* __restrict__ a2w,
    const float* __restrict__ a2b, float* __restrict__ s1, float* __restrict__ s2) {
    int id = blockIdx.x;
    int g = id & 7, s_ = id >> 3;
    int eh = s_ & 3;
    int row0 = ((s_ >> 2) * 8 + g) * 32;
    int t = threadIdx.x;
    int w = t >> 6, lane = t & 63;
    int m = lane & 15, quad = lane >> 4;

    __shared__ unsigned short stateL[32 * 136];

    // ---- embed via MFMA: state = relu(nodes @ Wemb + bemb) ----
    f32x4 accE[2][2];
#pragma unroll
    for (int mt = 0; mt < 2; ++mt)
#pragma unroll
        for (int nt = 0; nt < 2; ++nt) accE[mt][nt] = (f32x4){0.f, 0.f, 0.f, 0.f};
#pragma unroll
    for (int kt = 0; kt < 2; ++kt) {
        short8 aE[2], bE[2];
#pragma unroll
        for (int mt = 0; mt < 2; ++mt) {
            const float* np = nodes + (size_t)(row0 + mt * 16 + m) * NI + kt * 32 + quad * 8;
            f32x4 v0 = *(const f32x4*)np;
            f32x4 v1 = *(const f32x4*)(np + 4);
            union { unsigned us[4]; short8 s8; } pk;
#pragma unroll
            for (int r = 0; r < 2; ++r) {
                pk.us[r] = pack2bf(v0[2 * r], v0[2 * r + 1]);
                pk.us[r + 2] = pack2bf(v1[2 * r], v1[2 * r + 1]);
            }
            aE[mt] = pk.s8;
        }
#pragma unroll
        for (int nt = 0; nt < 2; ++nt)
            bE[nt] = *(const short8*)(WembT + (w * 32 + nt * 16 + m) * NI + kt * 32 + quad * 8);
#pragma unroll
        for (int mt = 0; mt < 2; ++mt)
#pragma unroll
            for (int nt = 0; nt < 2; ++nt)
                accE[mt][nt] =
                    __builtin_amdgcn_mfma_f32_16x16x32_bf16(aE[mt], bE[nt], accE[mt][nt], 0, 0, 0);
    }
#pragma unroll
    for (int mt = 0; mt < 2; ++mt)
#pragma unroll
        for (int nt = 0; nt < 2; ++nt) {
            int d = w * 32 + nt * 16 + m;
            float bb = bemb[d];
#pragma unroll
            for (int r = 0; r < 4; ++r) {
                float v = fmaxf(accE[mt][nt][r] + bb, 0.f);
                stateL[(mt * 16 + quad * 4 + r) * 136 + d] = f2bf(v);
            }
        }
    __syncthreads();

    // ---- main GEMM: Wh = state @ W0[eh], K=128, A from LDS ----
    f32x4 acc[2][2];
#pragma unroll
    for (int mt = 0; mt < 2; ++mt)
#pragma unroll
        for (int nt = 0; nt < 2; ++nt) acc[mt][nt] = (f32x4){0.f, 0.f, 0.f, 0.f};
#pragma unroll
    for (int k0 = 0; k0 < ND; k0 += 32) {
        short8 a[2], b[2];
#pragma unroll
        for (int mt = 0; mt < 2; ++mt)
            a[mt] = *(const short8*)&stateL[(mt * 16 + m) * 136 + k0 + quad * 8];
#pragma unroll
        for (int nt = 0; nt < 2; ++nt)
            b[nt] = *(const short8*)(W0T + ((size_t)(eh * ND + w * 32 + nt * 16 + m)) * ND +
                                     k0 + quad * 8);
#pragma unroll
        for (int mt = 0; mt < 2; ++mt)
#pragma unroll
            for (int nt = 0; nt < 2; ++nt)
                acc[mt][nt] =
                    __builtin_amdgcn_mfma_f32_16x16x32_bf16(a[mt], b[nt], acc[mt][nt], 0, 0, 0);
    }

    // ---- epilogue: store Wh fp32 + fused s1/s2 ----
    int b_ = row0 >> 10, i0b = row0 & 1023;
    int ehb = eh * NB + b_;
#pragma unroll
    for (int mt = 0; mt < 2; ++mt)
#pragma unroll
        for (int nt = 0; nt < 2; ++nt) {
            int d = w * 32 + nt * 16 + m;
            int i = i0b + mt * 16 + quad * 4;
            *(f32x4*)(Whf + (((size_t)ehb) * ND + d) * NN + i) = acc[mt][nt];
        }
    float w1a = a1w[eh * ND + w * 32 + m], w1b = a1w[eh * ND + w * 32 + 16 + m];
    float w2a = a2w[eh * ND + w * 32 + m], w2b = a2w[eh * ND + w * 32 + 16 + m];
    float p1[2][4], p2[2][4];
#pragma unroll
    for (int mt = 0; mt < 2; ++mt)
#pragma unroll
        for (int r = 0; r < 4; ++r) {
            p1[mt][r] = acc[mt][0][r] * w1a + acc[mt][1][r] * w1b;
            p2[mt][r] = acc[mt][0][r] * w2a + acc[mt][1][r] * w2b;
        }
#pragma unroll
    for (int off = 8; off >= 1; off >>= 1)
#pragma unroll
        for (int mt = 0; mt < 2; ++mt)
#pragma unroll
            for (int r = 0; r < 4; ++r) {
                p1[mt][r] += __shfl_xor(p1[mt][r], off);
                p2[mt][r] += __shfl_xor(p2[mt][r], off);
            }
    __shared__ float sred[2][4][4][8];
    if (m == 0) {
#pragma unroll
        for (int mt = 0; mt < 2; ++mt)
#pragma unroll
            for (int r = 0; r < 4; ++r) {
                sred[0][w][quad][mt * 4 + r] = p1[mt][r];
                sred[1][w][quad][mt * 4 + r] = p2[mt][r];
            }
    }
    __syncthreads();
    if (t < 32) {
        int mt = t >> 4, quad2 = (t >> 2) & 3, r = t & 3;
        int c = mt * 4 + r;
        float v = sred[0][0][quad2][c] + sred[0][1][quad2][c] + sred[0][2][quad2][c] +
                  sred[0][3][quad2][c];
        s1[(size_t)ehb * NN + i0b + t] = v + a1b[eh];
    } else if (t < 64) {
        int tl = t - 32;
        int mt = tl >> 4, quad2 = (tl >> 2) & 3, r = tl & 3;
        int c = mt * 4 + r;
        float v = sred[1][0][quad2][c] + sred[1][1][quad2][c] + sred[1][2][quad2][c] +
                  sred[1][3][quad2][c];
        s2[(size_t)ehb * NN + i0b + tl] = v + a2b[eh];
    }
}

// ---------------- layer-1 filter GEMM (K=512), stores Wh fp32 + s1/s2 ----------------
__global__ __launch_bounds__(256, 4) void whgemm1k(
    const unsigned short* __restrict__ state, const unsigned short* __restrict__ WT,
    float* __restrict__ Whf, const float* __restrict__ a1w,
    const float* __restrict__ a1b, const float* __restrict__ a2w,
    const float* __restrict__ a2b, float* __restrict__ s1, float* __restrict__ s2) {
    int id = blockIdx.x;
    int g = id & 7, s_ = id >> 3;
    int eh = s_ & 3;
    int row0 = ((s_ >> 2) * 8 + g) * 32;
    int t = threadIdx.x;
    int w = t >> 6, lane = t & 63;
    int m = lane & 15, quad = lane >> 4;

    f32x4 acc[2][2];
#pragma unroll
    for (int mt = 0; mt < 2; ++mt)
#pragma unroll
        for (int nt = 0; nt < 2; ++nt) acc[mt][nt] = (f32x4){0.f, 0.f, 0.f, 0.f};

    const unsigned short* Ab = state + (size_t)(row0 + m) * FIN1 + quad * 8;
    const unsigned short* Bb = WT + ((size_t)eh * ND + w * 32 + m) * FIN1 + quad * 8;
#pragma unroll 4
    for (int k0 = 0; k0 < FIN1; k0 += 32) {
        short8 a[2], b[2];
#pragma unroll
        for (int mt = 0; mt < 2; ++mt)
            a[mt] = *(const short8*)(Ab + (size_t)mt * 16 * FIN1 + k0);
#pragma unroll
        for (int nt = 0; nt < 2; ++nt)
            b[nt] = *(const short8*)(Bb + (size_t)nt * 16 * FIN1 + k0);
#pragma unroll
        for (int mt = 0; mt < 2; ++mt)
#pragma unroll
            for (int nt = 0; nt < 2; ++nt)
                acc[mt][nt] =
                    __builtin_amdgcn_mfma_f32_16x16x32_bf16(a[mt], b[nt], acc[mt][nt], 0, 0, 0);
    }
    int b_ = row0 >> 10, i0b = row0 & 1023;
    int ehb = eh * NB + b_;
#pragma unroll
    for (int mt = 0; mt < 2; ++mt)
#pragma unroll
        for (int nt = 0; nt < 2; ++nt) {
            int d = w * 32 + nt * 16 + m;
            int i = i0b + mt * 16 + quad * 4;
            *(f32x4*)(Whf + (((size_t)ehb) * ND + d) * NN + i) = acc[mt][nt];
        }
    float w1a = a1w[eh * ND + w * 32 + m], w1b = a1w[eh * ND + w * 32 + 16 + m];
    float w2a = a2w[eh * ND + w * 32 + m], w2b = a2w[eh * ND + w * 32 + 16 + m];
    float p1[2][4], p2[2][4];
#pragma unroll
    for (int mt = 0; mt < 2; ++mt)
#pragma unroll
        for (int r = 0; r < 4; ++r) {
            p1[mt][r] = acc[mt][0][r] * w1a + acc[mt][1][r] * w1b;
            p2[mt][r] = acc[mt][0][r] * w2a + acc[mt][1][r] * w2b;
        }
#pragma unroll
    for (int off = 8; off >= 1; off >>= 1)
#pragma unroll
        for (int mt = 0; mt < 2; ++mt)
#pragma unroll
            for (int r = 0; r < 4; ++r) {
                p1[mt][r] += __shfl_xor(p1[mt][r], off);
                p2[mt][r] += __shfl_xor(p2[mt][r], off);
            }
    __shared__ float sred[2][4][4][8];
    if (m == 0) {
#pragma unroll
        for (int mt = 0; mt < 2; ++mt)
#pragma unroll
            for (int r = 0; r < 4; ++r) {
                sred[0][w][quad][mt * 4 + r] = p1[mt][r];
                sred[1][w][quad][mt * 4 + r] = p2[mt][r];
            }
    }
    __syncthreads();
    if (t < 32) {
        int mt = t >> 4, quad2 = (t >> 2) & 3, r = t & 3;
        int c = mt * 4 + r;
        float v = sred[0][0][quad2][c] + sred[0][1][quad2][c] + sred[0][2][quad2][c] +
                  sred[0][3][quad2][c];
        s1[(size_t)ehb * NN + i0b + t] = v + a1b[eh];
    } else if (t < 64) {
        int tl = t - 32;
        int mt = tl >> 4, quad2 = (tl >> 2) & 3, r = tl & 3;
        int c = mt * 4 + r;
        float v = sred[1][0][quad2][c] + sred[1][1][quad2][c] + sred[1][2][quad2][c] +
                  sred[1][3][quad2][c];
        s2[(size_t)ehb * NN + i0b + tl] = v + a2b[eh];
    }
}

// ---------------- column sums + cache P bf16: Spart[ic][ehb][j], P[ehb][i][j] ----------
__global__ __launch_bounds__(256, 4) void colsumk(const float* __restrict__ edges,
                                                  const float* __restrict__ s1,
                                                  const float* __restrict__ s2,
                                                  float* __restrict__ Spart,
                                                  unsigned* __restrict__ Pbuf) {
    int jt = blockIdx.x, b = blockIdx.y, ic = blockIdx.z;
    int t = threadIdx.x;
    int jp = t & 31, is = t >> 5;          // j-pair, i-chunk (16 i each)
    int j = jt * 64 + jp * 2;
    __shared__ float s1L[4][128];
    for (int idx = t; idx < 512; idx += 256) {
        int eh = idx >> 7;
        s1L[eh][idx & 127] = s1[((size_t)eh * NB + b) * NN + ic * 128 + (idx & 127)];
    }
    __syncthreads();
    float s2v[4][2], acc4[4][2];
#pragma unroll
    for (int eh = 0; eh < 4; ++eh) {
        s2v[eh][0] = s2[((size_t)eh * NB + b) * NN + j];
        s2v[eh][1] = s2[((size_t)eh * NB + b) * NN + j + 1];
        acc4[eh][0] = 0.f;
        acc4[eh][1] = 0.f;
    }
    const float4* ep = (const float4*)edges +
                       (size_t)(b * NN + ic * 128 + is * 16) * (NN / 2) + jt * 32 + jp;
#pragma unroll 2
    for (int ii = 0; ii < 16; ++ii) {
        float4 ev = ep[(size_t)ii * (NN / 2)];   // (e0,e1)@j ; (e0,e1)@j+1
        int i = ic * 128 + is * 16 + ii;
#pragma unroll
        for (int eh = 0; eh < 4; ++eh) {
            float sv = s1L[eh][is * 16 + ii];
            float x0 = sv + s2v[eh][0];
            x0 = fmaxf(x0, 0.2f * x0);
            float p0 = __expf(x0 + (eh < 2 ? ev.x : ev.y));
            float x1 = sv + s2v[eh][1];
            x1 = fmaxf(x1, 0.2f * x1);
            float p1v = __expf(x1 + (eh < 2 ? ev.z : ev.w));
            acc4[eh][0] += p0;
            acc4[eh][1] += p1v;
            Pbuf[((size_t)(eh * NB + b) * NN + i) * (NN / 2) + jt * 32 + jp] =
                pack2bf(p0, p1v);
        }
    }
    __shared__ float red[8][4][64];  // [is][eh][jl]
#pragma unroll
    for (int eh = 0; eh < 4; ++eh) {
        red[is][eh][jp * 2] = acc4[eh][0];
        red[is][eh][jp * 2 + 1] = acc4[eh][1];
    }
    __syncthreads();
    if (t < 256) {
        int eho = t >> 6, jlo = t & 63;
        float Sv = 0.f;
#pragma unroll
        for (int isx = 0; isx < 8; ++isx) Sv += red[isx][eho][jlo];
        Spart[(((size_t)ic * EHC + eho) * NB + b) * NN + jt * 64 + jlo] = Sv;
    }
}

// ---------------- whnk: Whn[ehb][d][j] = bf16(Whf[ehb][d][j] / S_j) ----------------
__global__ __launch_bounds__(256) void whnk(const float* __restrict__ Whf,
                                            const float* __restrict__ Spart,
                                            unsigned short* __restrict__ Whn) {
    int blk = blockIdx.x;          // 256 = 32 ehb * 8 jc
    int ehb = blk & 31, jc = blk >> 5;
    int t = threadIdx.x;
    __shared__ float rS[128];
    if (t < 128) {
        int j = jc * 128 + t;
        const size_t pstr = (size_t)EHC * NB * NN;
        float S = 0.f;
#pragma unroll
        for (int ic = 0; ic < 8; ++ic) S += Spart[(size_t)ic * pstr + (size_t)ehb * NN + j];
        rS[t] = 1.f / S;
    }
    __syncthreads();
#pragma unroll
    for (int it = 0; it < 8; ++it) {
        int idx = it * 256 + t;
        int d = idx >> 4, jq = idx & 15;
        int j = jc * 128 + jq * 8;
        const float* wp = Whf + ((size_t)ehb * ND + d) * NN + j;
        f32x4 v0 = *(const f32x4*)wp;
        f32x4 v1 = *(const f32x4*)(wp + 4);
        u32x4 o;
        o[0] = pack2bf(v0[0] * rS[jq * 8 + 0], v0[1] * rS[jq * 8 + 1]);
        o[1] = pack2bf(v0[2] * rS[jq * 8 + 2], v0[3] * rS[jq * 8 + 3]);
        o[2] = pack2bf(v1[0] * rS[jq * 8 + 4], v1[1] * rS[jq * 8 + 5]);
        o[3] = pack2bf(v1[2] * rS[jq * 8 + 6], v1[3] * rS[jq * 8 + 7]);
        *(u32x4*)(Whn + ((size_t)ehb * ND + d) * NN + j) = o;
    }
}

// ---------------- msg: pipelined bf16 GEMM  C[d][i] = sum_j Whn[d,j] * P[i,j] ----------
// block: M=128 d (4 waves x 32), N=64 i, K=1024. Register ping-pong, no LDS.
__global__ __launch_bounds__(256, 4) void msgk(const unsigned short* __restrict__ Whn,
                                               const unsigned short* __restrict__ Pbuf,
                                               const float* __restrict__ sb,
                                               unsigned short* __restrict__ out0,
                                               float* __restrict__ out1, int mode) {
    int id = blockIdx.x;
    int ehb = id & 31;             // blocks sharing Whn (same ehb) -> same XCD (id%8 fixed)
    int it = id >> 5;              // 0..15
    int eh = ehb >> 3, b = ehb & 7;
    int i0 = it * 64;
    int t = threadIdx.x;
    int lane = t & 63, w = t >> 6;
    int m = lane & 15, quad = lane >> 4;

    f32x4 acc[2][4];               // [mt: d 16s][nt: i 16s]
#pragma unroll
    for (int mt = 0; mt < 2; ++mt)
#pragma unroll
        for (int nt = 0; nt < 4; ++nt) acc[mt][nt] = (f32x4){0.f, 0.f, 0.f, 0.f};

    const unsigned short* Ab = Whn + ((size_t)ehb * ND + w * 32 + m) * NN + quad * 8;
    const unsigned short* Pb = Pbuf + ((size_t)ehb * NN + i0 + m) * NN + quad * 8;

    short8 aA[2], bA[4], aB[2], bB[4];

    auto load = [&](short8* a, short8* bv, int k0) {
#pragma unroll
        for (int mt = 0; mt < 2; ++mt)
            a[mt] = *(const short8*)(Ab + (size_t)mt * 16 * NN + k0);
#pragma unroll
        for (int nt = 0; nt < 4; ++nt)
            bv[nt] = *(const short8*)(Pb + (size_t)nt * 16 * NN + k0);
    };
    auto step = [&](const short8* a, const short8* bv) {
#pragma unroll
        for (int mt = 0; mt < 2; ++mt)
#pragma unroll
            for (int nt = 0; nt < 4; ++nt)
                acc[mt][nt] =
                    __builtin_amdgcn_mfma_f32_16x16x32_bf16(a[mt], bv[nt], acc[mt][nt], 0, 0, 0);
    };

    load(aA, bA, 0);
    for (int kk = 0; kk < NN; kk += 64) {
        load(aB, bB, kk + 32);
        step(aA, bA);
        if (kk + 64 < NN) load(aA, bA, kk + 64);
        step(aB, bB);
    }

    // epilogue: C row(quad*4+r)=d (A side), col(m)=i (B side)
#pragma unroll
    for (int mt = 0; mt < 2; ++mt) {
        int d0 = w * 32 + mt * 16 + quad * 4;
        f32x4 sbv = *(const f32x4*)&sb[eh * ND + d0];
#pragma unroll
        for (int nt = 0; nt < 4; ++nt) {
            int i = i0 + nt * 16 + m;
            if (mode == 0) {
                union { unsigned us[2]; unsigned long long u64; } pk;
                pk.us[0] = pack2bf(acc[mt][nt][0] + sbv[0], acc[mt][nt][1] + sbv[1]);
                pk.us[1] = pack2bf(acc[mt][nt][2] + sbv[2], acc[mt][nt][3] + sbv[3]);
                *(unsigned long long*)(out0 + (size_t)(b * NN + i) * FIN1 + eh * ND + d0) =
                    pk.u64;
            } else {
                f32x4 vv;
#pragma unroll
                for (int r = 0; r < 4; ++r) {
                    float v = acc[mt][nt][r] + sbv[r];
                    vv[r] = v > 0.f ? v : expm1f(v);
                }
                *(f32x4*)(out1 + ((size_t)ehb * NN + i) * ND + d0) = vv;
            }
        }
    }
}

// ---------------- final: out = mean_eh(m1) @ Wout + bout (fused) ----------------
__global__ __launch_bounds__(256) void finalk(const float* __restrict__ m1,
                                              const float* __restrict__ Wout,
                                              const float* __restrict__ bout,
                                              float* __restrict__ out) {
    int row0 = blockIdx.x * 16;
    int t = threadIdx.x;
    __shared__ float sF[16 * ND];
    __shared__ float wL[ND * NO];
    const size_t str = (size_t)BN * ND;
    for (int idx = t; idx < 16 * ND; idx += 256) {
        size_t r = (size_t)row0 * ND + idx;
        sF[idx] = 0.25f * (m1[r] + m1[r + str] + m1[r + 2 * str] + m1[r + 3 * str]);
    }
    for (int idx = t; idx < ND * NO; idx += 256) wL[idx] = Wout[idx];
    __syncthreads();
    int o = t & 63;
    int rr = t >> 6;
    float bo = bout[o];
#pragma unroll
    for (int q = 0; q < 4; ++q) {
        int r = rr * 4 + q;
        float acc = 0.f;
#pragma unroll 4
        for (int d = 0; d < ND; ++d) acc += sF[r * ND + d] * wL[d * NO + o];
        out[(size_t)(row0 + r) * NO + o] = acc + bo;
    }
}

extern "C" void kernel_launch(void* const* d_in, const int* in_sizes, int n_in,
                              void* d_out, int out_size, void* d_ws, size_t ws_size,
                              hipStream_t stream) {
    const float* nodes = (const float*)d_in[0];
    const float* edges = (const float*)d_in[1];
    const float* Wemb = (const float*)d_in[2];
    const float* bemb = (const float*)d_in[3];
    const float* W0 = (const float*)d_in[4];
    const float* A1w0 = (const float*)d_in[5];
    const float* A1b0 = (const float*)d_in[6];
    const float* A2w0 = (const float*)d_in[7];
    const float* A2b0 = (const float*)d_in[8];
    const float* SB0 = (const float*)d_in[9];
    const float* W1 = (const float*)d_in[10];
    const float* A1w1 = (const float*)d_in[11];
    const float* A1b1 = (const float*)d_in[12];
    const float* A2w1 = (const float*)d_in[13];
    const float* A2b1 = (const float*)d_in[14];
    const float* SB1 = (const float*)d_in[15];
    const float* Wout = (const float*)d_in[16];
    const float* bout = (const float*)d_in[17];
    float* out = (float*)d_out;

    char* p = (char*)d_ws;
    auto alloc = [&](size_t bytes) {
        char* r = p;
        p += (bytes + 255) & ~(size_t)255;
        return r;
    };
    unsigned short* W0T = (unsigned short*)alloc((size_t)EHC * ND * ND * 2);
    unsigned short* W1T = (unsigned short*)alloc((size_t)EHC * ND * FIN1 * 2);
    unsigned short* WembT = (unsigned short*)alloc((size_t)ND * NI * 2);
    float* Whf = (float*)alloc((size_t)EHC * BN * ND * 4);
    unsigned short* Whn = (unsigned short*)alloc((size_t)EHC * BN * ND * 2);
    unsigned* Pbuf = (unsigned*)alloc((size_t)EHC * NB * NN * (NN / 2) * 4);
    unsigned short* state1 = (unsigned short*)alloc((size_t)BN * FIN1 * 2);
    float* s1b = (float*)alloc((size_t)EHC * BN * 4);
    float* s2b = (float*)alloc((size_t)EHC * BN * 4);
    float* Spart = (float*)alloc((size_t)8 * EHC * BN * 4);
    float* m1 = (float*)alloc((size_t)EHC * BN * ND * 4);

    prepTk<<<1312, 256, 0, stream>>>(W0, W1, Wemb, W0T, W1T, WembT);
    // layer 0
    embwh0k<<<1024, 256, 0, stream>>>(nodes, WembT, bemb, W0T, Whf, A1w0, A1b0, A2w0, A2b0,
                                      s1b, s2b);
    colsumk<<<dim3(NN / 64, NB, 8), 256, 0, stream>>>(edges, s1b, s2b, Spart, Pbuf);
    whnk<<<256, 256, 0, stream>>>(Whf, Spart, Whn);
    msgk<<<512, 256, 0, stream>>>(Whn, (const unsigned short*)Pbuf, SB0, state1, m1, 0);
    // layer 1
    whgemm1k<<<1024, 256, 0, stream>>>(state1, W1T, Whf, A1w1, A1b1, A2w1, A2b1, s1b, s2b);
    colsumk<<<dim3(NN / 64, NB, 8), 256, 0, stream>>>(edges, s1b, s2b, Spart, Pbuf);
    whnk<<<256, 256, 0, stream>>>(Whf, Spart, Whn);
    msgk<<<512, 256, 0, stream>>>(Whn, (const unsigned short*)Pbuf, SB1, state1, m1, 1);
    // head
    finalk<<<BN / 16, 256, 0, stream>>>(m1, Wout, bout, out);
}